// Round 7
// baseline (170.082 us; speedup 1.0000x reference)
//
#include <hip/hip_runtime.h>

// Problem constants: N=2, L=2048, E=1024, H=16, D=64
// ws: kc (n,h,c,d) | vcT (n,h,d,c) | ao (n,l,h*64+d) | Wob | excl | lmap |
// Wqb/Wkb/Wvb | po f32 partials @40MiB | ls f32 partial sums @80MiB.
//
// attn: Q-proj fused, K-range split 2-way (ksplit) -> 1024 blocks, 256 thr,
// KVBLK=64 dbuf, LDS 32KB -> 4 blocks/CU (4 independent barrier groups).
// Raw-exp2 softmax => splits combine exactly via (o0+o1)/(l0+l1) in a tiny
// BW-bound combine kernel.  out_proj back to 128x64 tiles (3 blocks/CU).

typedef __bf16 bf16_t;
typedef __bf16 bf16x4 __attribute__((ext_vector_type(4)));
typedef __bf16 bf16x8 __attribute__((ext_vector_type(8)));
typedef float f32x4 __attribute__((ext_vector_type(4)));
typedef unsigned int u32x4 __attribute__((ext_vector_type(4)));

#define MFMA16(a, b, c) __builtin_amdgcn_mfma_f32_16x16x32_bf16((a), (b), (c), 0, 0, 0)

#define GLOAD_LDS16(gp, lp)                                              \
    __builtin_amdgcn_global_load_lds(                                    \
        (const __attribute__((address_space(1))) void*)(gp),             \
        (__attribute__((address_space(3))) void*)(lp), 16, 0, 0)

__device__ inline bf16x8 cvt8(const float* __restrict__ p) {
    f32x4 a = *(const f32x4*)p;
    f32x4 b = *(const f32x4*)(p + 4);
    bf16x8 r;
    r[0] = (bf16_t)a[0]; r[1] = (bf16_t)a[1];
    r[2] = (bf16_t)a[2]; r[3] = (bf16_t)a[3];
    r[4] = (bf16_t)b[0]; r[5] = (bf16_t)b[1];
    r[6] = (bf16_t)b[2]; r[7] = (bf16_t)b[3];
    return r;
}

__device__ inline bf16x8 cvt8s(const f32x4 a, const f32x4 b) {
    bf16x8 r;
    r[0] = (bf16_t)a[0]; r[1] = (bf16_t)a[1];
    r[2] = (bf16_t)a[2]; r[3] = (bf16_t)a[3];
    r[4] = (bf16_t)b[0]; r[5] = (bf16_t)b[1];
    r[6] = (bf16_t)b[2]; r[7] = (bf16_t)b[3];
    return r;
}

// raw 2^x (scale log2(e) folded into Wqb prescale)
__device__ inline float exp2_fast(float x) {
    float r;
    asm("v_exp_f32 %0, %1" : "=v"(r) : "v"(x));
    return r;
}

// packed f32x2 -> bf16x2 (low = src0)
__device__ inline unsigned cvt_pk_bf16(float lo, float hi) {
    unsigned r;
    asm("v_cvt_pk_bf16_f32 %0, %1, %2" : "=v"(r) : "v"(lo), "v"(hi));
    return r;
}

// Cross-quad exchange (permlane32_swap then permlane16_swap).
__device__ inline void xchg_quads(unsigned &x, unsigned &y) {
    asm("v_permlane32_swap_b32 %0, %1\n\t"
        "v_permlane16_swap_b32 %0, %1"
        : "+v"(x), "+v"(y));
}

// ---------------------------------------------------------------------------
// Kernel 0: blocks 0-1: prefix scan + lmap.  Blocks 2-4: weight pre-convert.
// ---------------------------------------------------------------------------
__global__ __launch_bounds__(256) void scan_kernel(
    const int* __restrict__ msk, int* __restrict__ excl, int* __restrict__ lmap,
    const float* __restrict__ Wq, const float* __restrict__ Wk,
    const float* __restrict__ Wv,
    bf16_t* __restrict__ Wqb, bf16_t* __restrict__ Wkb, bf16_t* __restrict__ Wvb)
{
    const int t = threadIdx.x;

    if (blockIdx.x >= 2) {               // weight pre-convert
        const int wi = blockIdx.x - 2;
        const float* Ws = (wi == 0) ? Wq : (wi == 1) ? Wk : Wv;
        bf16_t* Wb = (wi == 0) ? Wqb : (wi == 1) ? Wkb : Wvb;
        const float scale = (wi == 0) ? 0.04508422f : 1.0f;   // log2(e)/32
        #pragma unroll
        for (int j = 0; j < 4; j++) {
            int idx = t * 16 + j * 4;
            f32x4 v = *(const f32x4*)&Ws[idx];
            bf16x4 r;
            r[0] = (bf16_t)(v[0] * scale); r[1] = (bf16_t)(v[1] * scale);
            r[2] = (bf16_t)(v[2] * scale); r[3] = (bf16_t)(v[3] * scale);
            *(bf16x4*)&Wb[idx] = r;
        }
        return;
    }

    __shared__ int wsum[4];
    const int n = blockIdx.x;
    const int lane = t & 63, w = t >> 6;
    const int* m = msk + n * 2048;
    int* e = excl + n * 2049;
    int* lm = lmap + n * 2048;

    int v[8], s = 0;
    #pragma unroll
    for (int j = 0; j < 8; j++) { v[j] = (m[t * 8 + j] != 0); s += v[j]; }

    int inc = s;
    #pragma unroll
    for (int d = 1; d < 64; d <<= 1) {
        int o = __shfl_up(inc, d);
        if (lane >= d) inc += o;
    }
    if (lane == 63) wsum[w] = inc;
    __syncthreads();
    int off = 0;
    #pragma unroll
    for (int i = 0; i < 4; i++)
        if (i < w) off += wsum[i];

    int a = off + inc - s;
    #pragma unroll
    for (int j = 0; j < 8; j++) {
        e[t * 8 + j] = a;
        if (v[j]) lm[a] = t * 8 + j;
        a += v[j];
    }
    if (t == 255) e[2048] = a;
}

// ---------------------------------------------------------------------------
// Kernel 1: K/V projections + Wo pre-convert (unchanged).
// ---------------------------------------------------------------------------
__global__ __launch_bounds__(256) void qkv_proj_kernel(
    const float* __restrict__ kin, const float* __restrict__ vin,
    const bf16_t* __restrict__ Wkb, const bf16_t* __restrict__ Wvb,
    const float* __restrict__ Wo,
    const int* __restrict__ excl, const int* __restrict__ lmap,
    bf16_t* __restrict__ kc, bf16_t* __restrict__ vcT, bf16_t* __restrict__ Wob)
{
    __shared__ __align__(16) char smem[51200];   // Xs[128][64]f32 | Ct2[128][72]bf16

    const int t = threadIdx.x;
    const int w = t >> 6, lane = t & 63, quad = lane >> 4, l16 = lane & 15;

    if (blockIdx.y == 2) {               // Wo cvt
        int idx = blockIdx.x * 1024 + t * 4;
        f32x4 v = *(const f32x4*)&Wo[idx];
        bf16x4 r;
        r[0] = (bf16_t)v[0]; r[1] = (bf16_t)v[1];
        r[2] = (bf16_t)v[2]; r[3] = (bf16_t)v[3];
        *(bf16x4*)&Wob[idx] = r;
        return;
    }

    if (blockIdx.y == 1) {               // V -> vcT (n,h,d,c) compacted domain
        bf16_t* Ct = (bf16_t*)smem;                   // [64][72]
        const int h = blockIdx.x & 15;
        const int ctile = blockIdx.x >> 4;            // [0,64)
        const int n = ctile >> 5;
        const int c0 = (ctile & 31) * 64;
        const int Lc = excl[n * 2049 + 2048];
        if (c0 >= Lc) return;

        const int p0 = w * 16 + l16;                  // compacted slot in tile
        int cs = c0 + p0; if (cs > Lc - 1) cs = Lc - 1;
        const int tg = lmap[n * 2048 + cs];           // original token
        const size_t rb = ((size_t)(n * 2048 + tg)) * 1024 + h * 64;

        bf16x8 b0 = cvt8(&vin[rb + quad * 8]);
        bf16x8 b1 = cvt8(&vin[rb + 32 + quad * 8]);

        #pragma unroll
        for (int nt = 0; nt < 4; nt++) {
            bf16x8 a0 = *(const bf16x8*)&Wvb[(nt * 16 + l16) * 64 + quad * 8];
            bf16x8 a1 = *(const bf16x8*)&Wvb[(nt * 16 + l16) * 64 + 32 + quad * 8];
            f32x4 acc = {0.f, 0.f, 0.f, 0.f};
            acc = MFMA16(a0, b0, acc);
            acc = MFMA16(a1, b1, acc);
            #pragma unroll
            for (int r = 0; r < 4; r++)          // C row = e_out, col = slot
                Ct[(nt * 16 + quad * 4 + r) * 72 + w * 16 + l16] = (bf16_t)acc[r];
        }
        __syncthreads();
        const int cnt = (Lc - c0 < 64) ? (Lc - c0) : 64;
        const size_t ob2 = ((size_t)(n * 16 + h)) * 131072 + c0;
        #pragma unroll
        for (int pass = 0; pass < 2; pass++) {
            int r = pass * 32 + (t >> 3);
            int cb8 = (t & 7) * 8;
            if (cb8 < cnt) {
                if (cb8 + 8 <= cnt) {
                    *(bf16x8*)&vcT[ob2 + (size_t)r * 2048 + cb8] =
                        *(const bf16x8*)&Ct[r * 72 + cb8];
                } else {
                    for (int q = cb8; q < cnt; q++)
                        vcT[ob2 + (size_t)r * 2048 + q] = Ct[r * 72 + q];
                }
            }
        }
        return;
    }

    // ---- y=0: K (compacted rows), 128 rows/block ----
    if (blockIdx.x >= 512) return;
    const int n = blockIdx.x >> 8;                // 256 blocks per batch
    const int c0 = (blockIdx.x & 255) * 8;        // 8 compacted tokens x 16 heads
    const int Lc = excl[n * 2049 + 2048];
    if (c0 >= Lc) return;

    float* Xs = (float*)smem;                         // [128][64] fp32, swizzled
    bf16_t* Ct2 = (bf16_t*)(smem + 32768);            // [128][72]

    #pragma unroll
    for (int j = 0; j < 8; j++) {
        int br = w * 32 + j * 4;
        int srow = br + (lane >> 4);
        int scol = ((lane & 15) ^ (srow & 15)) * 4;
        int csx = c0 + (srow >> 4); if (csx > Lc - 1) csx = Lc - 1;
        int hs = srow & 15;
        int ls = lmap[n * 2048 + csx];
        GLOAD_LDS16(&kin[((size_t)((n * 2048 + ls) * 16 + hs)) * 64 + scol], &Xs[br * 64]);
    }
    __syncthreads();

    const int rbase = w * 32;
    bf16x8 a[2][2];
    #pragma unroll
    for (int qs = 0; qs < 2; qs++) {
        int row = rbase + qs * 16 + l16;
        const char* rowp = (const char*)Xs + (size_t)row * 256;
        int swb = (row & 15) << 4;
        #pragma unroll
        for (int c = 0; c < 2; c++) {
            f32x4 lo = *(const f32x4*)(rowp + ((c * 128 + quad * 32) ^ swb));
            f32x4 hi = *(const f32x4*)(rowp + ((c * 128 + quad * 32 + 16) ^ swb));
            a[qs][c] = cvt8s(lo, hi);
        }
    }

    f32x4 acc[4][2];
    #pragma unroll
    for (int nt = 0; nt < 4; nt++) {
        bf16x8 b0 = *(const bf16x8*)&Wkb[(nt * 16 + l16) * 64 + quad * 8];
        bf16x8 b1 = *(const bf16x8*)&Wkb[(nt * 16 + l16) * 64 + 32 + quad * 8];
        #pragma unroll
        for (int qs = 0; qs < 2; qs++) {
            f32x4 z = {0.f, 0.f, 0.f, 0.f};
            z = MFMA16(a[qs][0], b0, z);
            z = MFMA16(a[qs][1], b1, z);
            acc[nt][qs] = z;
        }
    }

    #pragma unroll
    for (int nt = 0; nt < 4; nt++)
        #pragma unroll
        for (int qs = 0; qs < 2; qs++)
            #pragma unroll
            for (int r = 0; r < 4; r++)
                Ct2[(rbase + qs * 16 + quad * 4 + r) * 72 + nt * 16 + l16] = (bf16_t)acc[nt][qs][r];
    __syncthreads();

    #pragma unroll
    for (int it = 0; it < 4; it++) {
        int j = it * 32 + (t >> 3);
        bf16x8 val = *(const bf16x8*)&Ct2[j * 72 + (t & 7) * 8];
        int c = c0 + (j >> 4), h2 = j & 15;
        if (c < Lc)
            *(bf16x8*)&kc[(((size_t)(n * 16 + h2)) * 2048 + c) * 64 + (t & 7) * 8] = val;
    }
}

// ---------------------------------------------------------------------------
// Kernel 2: fused Q-proj + flash attention, K-range SPLIT 2-way.
// 1024 blocks x 256 thr, KVBLK=64 dbuf, LDS 32KB -> 4 blocks/CU.
// Writes raw partial o (f32) + partial lsum; combine_kernel finishes.
// ---------------------------------------------------------------------------
__global__ __launch_bounds__(256) void attn_kernel(
    const float* __restrict__ qin, const bf16_t* __restrict__ Wqb,
    const bf16_t* __restrict__ kc, const bf16_t* __restrict__ vcT,
    const int* __restrict__ excl, float* __restrict__ po, float* __restrict__ ls)
{
    __shared__ __align__(16) char smem[32768];
    bf16_t* KtP = (bf16_t*)smem;              // [2][64][64]
    bf16_t* VtP = (bf16_t*)(smem + 16384);    // [2][64][64]
#define KT(buf, r, c) KtP[(buf) * 4096 + (r) * 64 + (c)]
#define VT(buf, r, c) VtP[(buf) * 4096 + (r) * 64 + (c)]

    const int t = threadIdx.x;
    const int w = t >> 6, lane = t & 63, quad = lane >> 4, l16 = lane & 15;

    const int flat = blockIdx.x;              // [0,1024)
    const int xcd = flat & 7, slot = flat >> 3;      // slot [0,128)
    const int nh = xcd * 4 + (slot >> 5);            // [0,32)
    const int qb = (slot >> 1) & 15;
    const int s  = slot & 1;                         // K-split half
    const int n = nh >> 4, h = nh & 15;
    const size_t nhbase = (size_t)nh * 131072;

    const int Lc = excl[n * 2049 + 2048];
    const int ntot  = (Lc + 63) >> 6;
    const int nhalf = (ntot + 1) >> 1;
    const int tile0 = s ? nhalf : 0;
    const int tile1 = s ? ntot : nhalf;
    const int rbase = w * 32;
    const int qbase = qb * 128 + rbase;

    // ---- Q projection prologue (Xq overlays whole smem; Qt overlays Vt) ---
    bf16x8 aq[2][2];
    {
        float* Xq = (float*)smem;                 // [128][64] fp32, swizzled
        bf16_t* Qt = (bf16_t*)(smem + 16384);     // [128][64] bf16, swizzled
        const int qrow0 = qb * 128;
        #pragma unroll
        for (int j = 0; j < 8; j++) {
            int br = w * 32 + j * 4;
            int srow = br + (lane >> 4);
            int scol = ((lane & 15) ^ (srow & 15)) * 4;
            GLOAD_LDS16(&qin[((size_t)(n * 2048 + qrow0 + srow)) * 1024 + h * 64 + scol],
                        &Xq[br * 64]);
        }
        __syncthreads();

        bf16x8 a[2][2];
        #pragma unroll
        for (int qs = 0; qs < 2; qs++) {
            int row = rbase + qs * 16 + l16;
            const char* rowp = (const char*)Xq + (size_t)row * 256;
            int swb = (row & 15) << 4;
            #pragma unroll
            for (int c = 0; c < 2; c++) {
                f32x4 lo = *(const f32x4*)(rowp + ((c * 128 + quad * 32) ^ swb));
                f32x4 hi = *(const f32x4*)(rowp + ((c * 128 + quad * 32 + 16) ^ swb));
                a[qs][c] = cvt8s(lo, hi);
            }
        }
        __syncthreads();   // all Xq reads done before Qt writes clobber Xq hi

        f32x4 pacc[4][2];
        #pragma unroll
        for (int nt = 0; nt < 4; nt++) {
            bf16x8 b0 = *(const bf16x8*)&Wqb[(nt * 16 + l16) * 64 + quad * 8];
            bf16x8 b1 = *(const bf16x8*)&Wqb[(nt * 16 + l16) * 64 + 32 + quad * 8];
            #pragma unroll
            for (int qs = 0; qs < 2; qs++) {
                f32x4 z = {0.f, 0.f, 0.f, 0.f};
                z = MFMA16(a[qs][0], b0, z);
                z = MFMA16(a[qs][1], b1, z);
                pacc[nt][qs] = z;
            }
        }
        #pragma unroll
        for (int nt = 0; nt < 4; nt++)
            #pragma unroll
            for (int qs = 0; qs < 2; qs++)
                #pragma unroll
                for (int r = 0; r < 4; r++) {
                    int row = rbase + qs * 16 + quad * 4 + r;
                    int col = nt * 16 + l16;
                    int byteoff = row * 128 + ((((col >> 3) ^ (row & 7)) << 4) | ((col & 7) << 1));
                    *(bf16_t*)((char*)Qt + byteoff) = (bf16_t)pacc[nt][qs][r];
                }
        __syncthreads();
        #pragma unroll
        for (int qs = 0; qs < 2; qs++) {
            int row = rbase + qs * 16 + l16;
            #pragma unroll
            for (int c = 0; c < 2; c++)
                aq[qs][c] = *(const bf16x8*)((const char*)Qt + row * 128 +
                                             (((c * 4 + quad) ^ (row & 7)) << 4));
        }
        __syncthreads();   // Qt reads done before K/V staging overwrites
    }

    f32x4 o[2][4];
    float lsum[2] = {0.f, 0.f};
    #pragma unroll
    for (int qs = 0; qs < 2; qs++)
        #pragma unroll
        for (int dt = 0; dt < 4; dt++) {
            o[qs][dt][0] = 0.f; o[qs][dt][1] = 0.f; o[qs][dt][2] = 0.f; o[qs][dt][3] = 0.f;
        }

    // staging source swizzles
    const int ksrow = lane >> 3;
    const int kscol = ((lane & 7) ^ (lane >> 3)) * 8;
    // read swizzles
    const int swr = l16 & 7;
    const int ck0 = (quad ^ swr) * 8;
    const int ck1 = ((quad + 4) ^ swr) * 8;

#define STAGE_KV(buf, kn)                                                     \
    {                                                                         \
        _Pragma("unroll")                                                     \
        for (int j = 0; j < 2; j++) {                                         \
            int rb = w * 16 + j * 8;                                          \
            GLOAD_LDS16(&kc[nhbase + (size_t)((kn) + rb + ksrow) * 64 + kscol],\
                        &KT(buf, rb, 0));                                     \
            GLOAD_LDS16(&vcT[nhbase + (size_t)(rb + ksrow) * 2048 + (kn) + kscol],\
                        &VT(buf, rb, 0));                                     \
        }                                                                     \
    }

    if (tile0 < tile1) STAGE_KV(0, tile0 * 64);

    for (int i = tile0; i < tile1; i++) {
        const int cb = (i - tile0) & 1, nb = cb ^ 1;
        const int k0 = i * 64;
        __syncthreads();

        if (i + 1 < tile1) STAGE_KV(nb, k0 + 64);

        // QK^T: lane (quad,l16) gets P[k = k0 + ct*16+quad*4+r][q = l16]
        f32x4 st[2][4];
        __builtin_amdgcn_s_setprio(1);
        #pragma unroll
        for (int ct = 0; ct < 4; ct++) {
            bf16x8 kb0 = *(const bf16x8*)&KT(cb, ct * 16 + l16, ck0);
            bf16x8 kb1 = *(const bf16x8*)&KT(cb, ct * 16 + l16, ck1);
            #pragma unroll
            for (int qs = 0; qs < 2; qs++) {
                f32x4 acc = {0.f, 0.f, 0.f, 0.f};
                acc = MFMA16(kb0, aq[qs][0], acc);
                acc = MFMA16(kb1, aq[qs][1], acc);
                st[qs][ct] = acc;
            }
        }
        __builtin_amdgcn_s_setprio(0);

        // softmax numerator: p = 2^score (log2e folded into Wqb)
        if (k0 + 64 <= Lc) {
            #pragma unroll
            for (int qs = 0; qs < 2; qs++)
                #pragma unroll
                for (int ct = 0; ct < 4; ct++)
                    #pragma unroll
                    for (int r = 0; r < 4; r++) {
                        float p = exp2_fast(st[qs][ct][r]);
                        lsum[qs] += p;
                        st[qs][ct][r] = p;
                    }
        } else {
            #pragma unroll
            for (int qs = 0; qs < 2; qs++)
                #pragma unroll
                for (int ct = 0; ct < 4; ct++)
                    #pragma unroll
                    for (int r = 0; r < 4; r++) {
                        int kk = k0 + ct * 16 + quad * 4 + r;
                        float p = (kk < Lc) ? exp2_fast(st[qs][ct][r]) : 0.0f;
                        lsum[qs] += p;
                        st[qs][ct][r] = p;
                    }
        }

        // in-register P -> B-operand redistribution (cvt_pk + permlane)
        bf16x8 bp[2][2];
        #pragma unroll
        for (int qs = 0; qs < 2; qs++) {
            unsigned u[4][2];
            #pragma unroll
            for (int ct = 0; ct < 4; ct++) {
                u[ct][0] = cvt_pk_bf16(st[qs][ct][0], st[qs][ct][1]);
                u[ct][1] = cvt_pk_bf16(st[qs][ct][2], st[qs][ct][3]);
            }
            #pragma unroll
            for (int hh = 0; hh < 2; hh++) {
                unsigned b0 = u[2 * hh][0], b2 = u[2 * hh + 1][0];
                xchg_quads(b0, b2);
                unsigned b1 = u[2 * hh][1], b3 = u[2 * hh + 1][1];
                xchg_quads(b1, b3);
                u32x4 q4 = {b0, b1, b2, b3};
                bp[qs][hh] = __builtin_bit_cast(bf16x8, q4);
            }
        }

        __builtin_amdgcn_s_setprio(1);
        #pragma unroll
        for (int dt = 0; dt < 4; dt++) {
            bf16x8 va0 = *(const bf16x8*)&VT(cb, dt * 16 + l16, ck0);
            bf16x8 va1 = *(const bf16x8*)&VT(cb, dt * 16 + l16, ck1);
            #pragma unroll
            for (int qs = 0; qs < 2; qs++) {
                o[qs][dt] = MFMA16(va0, bp[qs][0], o[qs][dt]);
                o[qs][dt] = MFMA16(va1, bp[qs][1], o[qs][dt]);
            }
        }
        __builtin_amdgcn_s_setprio(0);
    }

    // write raw partial o + partial lsum (combine kernel normalizes)
    #pragma unroll
    for (int qs = 0; qs < 2; qs++) {
        float v = lsum[qs];
        v += __shfl_xor(v, 16);
        v += __shfl_xor(v, 32);
        const int q = qbase + qs * 16 + l16;
        const size_t pbase = ((size_t)(nh * 2 + s) * 2048 + q) * 64;
        #pragma unroll
        for (int dt = 0; dt < 4; dt++)
            *(f32x4*)&po[pbase + dt * 16 + quad * 4] = o[qs][dt];
        if (lane < 16) ls[(size_t)(nh * 2 + s) * 2048 + q] = v;
    }
#undef KT
#undef VT
#undef STAGE_KV
}

// ---------------------------------------------------------------------------
// Kernel 2b: combine split partials: ao = (o0+o1)/(l0+l1), cvt to bf16.
// ---------------------------------------------------------------------------
__global__ __launch_bounds__(256) void combine_kernel(
    const float* __restrict__ po, const float* __restrict__ ls,
    bf16_t* __restrict__ ao)
{
    const int t = threadIdx.x;
    const int nh = blockIdx.x >> 6;           // 32 nh x 64 q-chunks
    const int qblk = blockIdx.x & 63;
    const int n = nh >> 4, h = nh & 15;
    const int q = qblk * 32 + (t >> 3);
    const int dc = (t & 7) * 8;

    float l0 = ls[(size_t)(nh * 2) * 2048 + q];
    float l1 = ls[(size_t)(nh * 2 + 1) * 2048 + q];
    float inv = 1.0f / (l0 + l1);

    size_t b0 = ((size_t)(nh * 2) * 2048 + q) * 64 + dc;
    size_t b1 = ((size_t)(nh * 2 + 1) * 2048 + q) * 64 + dc;
    f32x4 a0 = *(const f32x4*)&po[b0];
    f32x4 a1 = *(const f32x4*)&po[b0 + 4];
    f32x4 c0 = *(const f32x4*)&po[b1];
    f32x4 c1 = *(const f32x4*)&po[b1 + 4];

    bf16x8 r;
    r[0] = (bf16_t)((a0[0] + c0[0]) * inv);
    r[1] = (bf16_t)((a0[1] + c0[1]) * inv);
    r[2] = (bf16_t)((a0[2] + c0[2]) * inv);
    r[3] = (bf16_t)((a0[3] + c0[3]) * inv);
    r[4] = (bf16_t)((a1[0] + c1[0]) * inv);
    r[5] = (bf16_t)((a1[1] + c1[1]) * inv);
    r[6] = (bf16_t)((a1[2] + c1[2]) * inv);
    r[7] = (bf16_t)((a1[3] + c1[3]) * inv);
    *(bf16x8*)&ao[((size_t)n * 2048 + q) * 1024 + h * 64 + dc] = r;
}

// ---------------------------------------------------------------------------
// Kernel 3: out = X @ Wob^T + bo. 128x64 tiles, 512 blocks (3 blocks/CU).
// ---------------------------------------------------------------------------
__global__ __launch_bounds__(256, 2) void out_proj_kernel(
    const bf16_t* __restrict__ X, const bf16_t* __restrict__ Wob,
    const float* __restrict__ bo, float* __restrict__ out)
{
    __shared__ bf16_t Xs[2][128][64];
    __shared__ bf16_t Ws[2][64][64];

    const int t = threadIdx.x;
    const int w = t >> 6, lane = t & 63, quad = lane >> 4, l16 = lane & 15;
    const int Mbase = blockIdx.x * 128;
    const int Nbase = blockIdx.y * 64;
    const int mrow = (w & 1) * 64;
    const int ncol = (w >> 1) * 32;

    const int scol = ((lane & 7) ^ (lane >> 3)) * 8;
    const int swr  = l16 & 7;

    f32x4 acc[4][2];
    #pragma unroll
    for (int mi = 0; mi < 4; mi++)
        #pragma unroll
        for (int ni = 0; ni < 2; ni++) {
            acc[mi][ni][0] = 0.f; acc[mi][ni][1] = 0.f;
            acc[mi][ni][2] = 0.f; acc[mi][ni][3] = 0.f;
        }

    #pragma unroll
    for (int j = 0; j < 4; j++) {
        int br = w * 32 + j * 8;
        GLOAD_LDS16(&X[(size_t)(Mbase + br + (lane >> 3)) * 1024 + scol], &Xs[0][br][0]);
    }
    #pragma unroll
    for (int j = 0; j < 2; j++) {
        int br = w * 16 + j * 8;
        GLOAD_LDS16(&Wob[(size_t)(Nbase + br + (lane >> 3)) * 1024 + scol], &Ws[0][br][0]);
    }

    for (int i = 0; i < 16; i++) {
        const int cb = i & 1, nb = cb ^ 1;
        __syncthreads();

        if (i < 15) {
            const int kn = (i + 1) * 64;
            #pragma unroll
            for (int j = 0; j < 4; j++) {
                int br = w * 32 + j * 8;
                GLOAD_LDS16(&X[(size_t)(Mbase + br + (lane >> 3)) * 1024 + kn + scol],
                            &Xs[nb][br][0]);
            }
            #pragma unroll
            for (int j = 0; j < 2; j++) {
                int br = w * 16 + j * 8;
                GLOAD_LDS16(&Wob[(size_t)(Nbase + br + (lane >> 3)) * 1024 + kn + scol],
                            &Ws[nb][br][0]);
            }
        }

        #pragma unroll
        for (int c = 0; c < 2; c++) {
            bf16x8 bfr[2];
            #pragma unroll
            for (int ni = 0; ni < 2; ni++)
                bfr[ni] = *(const bf16x8*)&Ws[cb][ncol + ni * 16 + l16][((c * 4 + quad) ^ swr) * 8];
            #pragma unroll
            for (int mi = 0; mi < 4; mi++) {
                bf16x8 afr = *(const bf16x8*)&Xs[cb][mrow + mi * 16 + l16][((c * 4 + quad) ^ swr) * 8];
                #pragma unroll
                for (int ni = 0; ni < 2; ni++)
                    acc[mi][ni] = MFMA16(afr, bfr[ni], acc[mi][ni]);
            }
        }
    }

    #pragma unroll
    for (int ni = 0; ni < 2; ni++) {
        float b = bo[Nbase + ncol + ni * 16 + l16];
        #pragma unroll
        for (int mi = 0; mi < 4; mi++) {
            #pragma unroll
            for (int r = 0; r < 4; r++) {
                int row = Mbase + mrow + mi * 16 + quad * 4 + r;
                out[(size_t)row * 1024 + Nbase + ncol + ni * 16 + l16] = acc[mi][ni][r] + b;
            }
        }
    }
}

// ---------------------------------------------------------------------------
extern "C" void kernel_launch(void* const* d_in, const int* in_sizes, int n_in,
                              void* d_out, int out_size, void* d_ws, size_t ws_size,
                              hipStream_t stream)
{
    const float* qin = (const float*)d_in[0];
    const float* kin = (const float*)d_in[1];
    const float* vin = (const float*)d_in[2];
    const int*   msk = (const int*)d_in[3];
    const float* Wq  = (const float*)d_in[4];
    const float* Wk  = (const float*)d_in[5];
    const float* Wv  = (const float*)d_in[6];
    const float* Wo  = (const float*)d_in[7];
    const float* bo  = (const float*)d_in[8];
    float* out = (float*)d_out;

    bf16_t* ws  = (bf16_t*)d_ws;
    bf16_t* kc  = ws + 4194304;        // (n,h,c,d)  4M (first Lc rows valid)
    bf16_t* vcT = ws + 8388608;        // (n,h,d,c)  4M (first Lc cols valid)
    bf16_t* ao  = ws + 12582912;       // (n,l,h*64+d) 4M
    bf16_t* Wob = ws + 16777216;       // bf16 Wo   1M
    int* excl   = (int*)(ws + 17825792);  // 2 x 2049 ints
    int* lmap   = excl + 4100;            // 2 x 2048 ints (compacted -> token)
    bf16_t* Wqb = (bf16_t*)(lmap + 4096); // 64x64 bf16 (scaled)
    bf16_t* Wkb = Wqb + 4096;
    bf16_t* Wvb = Wkb + 4096;
    float* po   = (float*)((char*)d_ws + (40u << 20));  // (nh,s,q,64) f32, 33.5MB
    float* ls   = (float*)((char*)d_ws + (80u << 20));  // (nh,s,q) f32, 0.5MB

    scan_kernel<<<5, 256, 0, stream>>>(msk, excl, lmap, Wq, Wk, Wv, Wqb, Wkb, Wvb);
    qkv_proj_kernel<<<dim3(1024, 3), 256, 0, stream>>>(kin, vin, Wkb, Wvb, Wo,
                                                        excl, lmap, kc, vcT, Wob);
    attn_kernel<<<dim3(1024), 256, 0, stream>>>(qin, Wqb, kc, vcT, excl, po, ls);
    combine_kernel<<<dim3(2048), 256, 0, stream>>>(po, ls, ao);
    out_proj_kernel<<<dim3(32, 16), 256, 0, stream>>>(ao, Wob, bo, out);
}

// Round 8
// 154.362 us; speedup vs baseline: 1.1018x; 1.1018x over previous
//
#include <hip/hip_runtime.h>

// Problem constants: N=2, L=2048, E=1024, H=16, D=64
// ws: kc (n,h,c,d) | vcT (n,h,d,c) | ao (n,l,h*64+d) | Wob | excl | lmap |
// Wqb/Wkb/Wvb bf16 (Wqb pre-scaled by log2(e)/32).
//
// attn: Q-proj fused (disjoint 128x64 slice per block), 8 waves/block,
// KVBLK=128 double-buffered, XOR-swizzled tiles, in-register P exchange,
// softmax denominator via ones-row MFMA (no scalar lsum chain).
// K/V projections in COMPACTED token domain via lmap.

typedef __bf16 bf16_t;
typedef __bf16 bf16x4 __attribute__((ext_vector_type(4)));
typedef __bf16 bf16x8 __attribute__((ext_vector_type(8)));
typedef float f32x4 __attribute__((ext_vector_type(4)));
typedef unsigned int u32x4 __attribute__((ext_vector_type(4)));

#define MFMA16(a, b, c) __builtin_amdgcn_mfma_f32_16x16x32_bf16((a), (b), (c), 0, 0, 0)

#define GLOAD_LDS16(gp, lp)                                              \
    __builtin_amdgcn_global_load_lds(                                    \
        (const __attribute__((address_space(1))) void*)(gp),             \
        (__attribute__((address_space(3))) void*)(lp), 16, 0, 0)

__device__ inline bf16x8 cvt8(const float* __restrict__ p) {
    f32x4 a = *(const f32x4*)p;
    f32x4 b = *(const f32x4*)(p + 4);
    bf16x8 r;
    r[0] = (bf16_t)a[0]; r[1] = (bf16_t)a[1];
    r[2] = (bf16_t)a[2]; r[3] = (bf16_t)a[3];
    r[4] = (bf16_t)b[0]; r[5] = (bf16_t)b[1];
    r[6] = (bf16_t)b[2]; r[7] = (bf16_t)b[3];
    return r;
}

__device__ inline bf16x8 cvt8s(const f32x4 a, const f32x4 b) {
    bf16x8 r;
    r[0] = (bf16_t)a[0]; r[1] = (bf16_t)a[1];
    r[2] = (bf16_t)a[2]; r[3] = (bf16_t)a[3];
    r[4] = (bf16_t)b[0]; r[5] = (bf16_t)b[1];
    r[6] = (bf16_t)b[2]; r[7] = (bf16_t)b[3];
    return r;
}

// raw 2^x (scale log2(e) folded into Wqb prescale)
__device__ inline float exp2_fast(float x) {
    float r;
    asm("v_exp_f32 %0, %1" : "=v"(r) : "v"(x));
    return r;
}

// packed f32x2 -> bf16x2 (low = src0)
__device__ inline unsigned cvt_pk_bf16(float lo, float hi) {
    unsigned r;
    asm("v_cvt_pk_bf16_f32 %0, %1, %2" : "=v"(r) : "v"(lo), "v"(hi));
    return r;
}

// Cross-quad exchange (permlane32_swap then permlane16_swap).
__device__ inline void xchg_quads(unsigned &x, unsigned &y) {
    asm("v_permlane32_swap_b32 %0, %1\n\t"
        "v_permlane16_swap_b32 %0, %1"
        : "+v"(x), "+v"(y));
}

// ---------------------------------------------------------------------------
// Kernel 0: blocks 0-1: prefix scan + lmap.  Blocks 2-4: weight pre-convert.
// ---------------------------------------------------------------------------
__global__ __launch_bounds__(256) void scan_kernel(
    const int* __restrict__ msk, int* __restrict__ excl, int* __restrict__ lmap,
    const float* __restrict__ Wq, const float* __restrict__ Wk,
    const float* __restrict__ Wv,
    bf16_t* __restrict__ Wqb, bf16_t* __restrict__ Wkb, bf16_t* __restrict__ Wvb)
{
    const int t = threadIdx.x;

    if (blockIdx.x >= 2) {               // weight pre-convert
        const int wi = blockIdx.x - 2;
        const float* Ws = (wi == 0) ? Wq : (wi == 1) ? Wk : Wv;
        bf16_t* Wb = (wi == 0) ? Wqb : (wi == 1) ? Wkb : Wvb;
        const float scale = (wi == 0) ? 0.04508422f : 1.0f;   // log2(e)/32
        #pragma unroll
        for (int j = 0; j < 4; j++) {
            int idx = t * 16 + j * 4;
            f32x4 v = *(const f32x4*)&Ws[idx];
            bf16x4 r;
            r[0] = (bf16_t)(v[0] * scale); r[1] = (bf16_t)(v[1] * scale);
            r[2] = (bf16_t)(v[2] * scale); r[3] = (bf16_t)(v[3] * scale);
            *(bf16x4*)&Wb[idx] = r;
        }
        return;
    }

    __shared__ int wsum[4];
    const int n = blockIdx.x;
    const int lane = t & 63, w = t >> 6;
    const int* m = msk + n * 2048;
    int* e = excl + n * 2049;
    int* lm = lmap + n * 2048;

    int v[8], s = 0;
    #pragma unroll
    for (int j = 0; j < 8; j++) { v[j] = (m[t * 8 + j] != 0); s += v[j]; }

    int inc = s;
    #pragma unroll
    for (int d = 1; d < 64; d <<= 1) {
        int o = __shfl_up(inc, d);
        if (lane >= d) inc += o;
    }
    if (lane == 63) wsum[w] = inc;
    __syncthreads();
    int off = 0;
    #pragma unroll
    for (int i = 0; i < 4; i++)
        if (i < w) off += wsum[i];

    int a = off + inc - s;
    #pragma unroll
    for (int j = 0; j < 8; j++) {
        e[t * 8 + j] = a;
        if (v[j]) lm[a] = t * 8 + j;
        a += v[j];
    }
    if (t == 255) e[2048] = a;
}

// ---------------------------------------------------------------------------
// Kernel 1: K/V projections + Wo pre-convert.
// ---------------------------------------------------------------------------
__global__ __launch_bounds__(256) void qkv_proj_kernel(
    const float* __restrict__ kin, const float* __restrict__ vin,
    const bf16_t* __restrict__ Wkb, const bf16_t* __restrict__ Wvb,
    const float* __restrict__ Wo,
    const int* __restrict__ excl, const int* __restrict__ lmap,
    bf16_t* __restrict__ kc, bf16_t* __restrict__ vcT, bf16_t* __restrict__ Wob)
{
    __shared__ __align__(16) char smem[51200];   // Xs[128][64]f32 | Ct2[128][72]bf16

    const int t = threadIdx.x;
    const int w = t >> 6, lane = t & 63, quad = lane >> 4, l16 = lane & 15;

    if (blockIdx.y == 2) {               // Wo cvt
        int idx = blockIdx.x * 1024 + t * 4;
        f32x4 v = *(const f32x4*)&Wo[idx];
        bf16x4 r;
        r[0] = (bf16_t)v[0]; r[1] = (bf16_t)v[1];
        r[2] = (bf16_t)v[2]; r[3] = (bf16_t)v[3];
        *(bf16x4*)&Wob[idx] = r;
        return;
    }

    if (blockIdx.y == 1) {               // V -> vcT (n,h,d,c) compacted domain
        bf16_t* Ct = (bf16_t*)smem;                   // [64][72]
        const int h = blockIdx.x & 15;
        const int ctile = blockIdx.x >> 4;            // [0,64)
        const int n = ctile >> 5;
        const int c0 = (ctile & 31) * 64;
        const int Lc = excl[n * 2049 + 2048];
        if (c0 >= Lc) return;

        const int p0 = w * 16 + l16;                  // compacted slot in tile
        int cs = c0 + p0; if (cs > Lc - 1) cs = Lc - 1;
        const int tg = lmap[n * 2048 + cs];           // original token
        const size_t rb = ((size_t)(n * 2048 + tg)) * 1024 + h * 64;

        bf16x8 b0 = cvt8(&vin[rb + quad * 8]);
        bf16x8 b1 = cvt8(&vin[rb + 32 + quad * 8]);

        #pragma unroll
        for (int nt = 0; nt < 4; nt++) {
            bf16x8 a0 = *(const bf16x8*)&Wvb[(nt * 16 + l16) * 64 + quad * 8];
            bf16x8 a1 = *(const bf16x8*)&Wvb[(nt * 16 + l16) * 64 + 32 + quad * 8];
            f32x4 acc = {0.f, 0.f, 0.f, 0.f};
            acc = MFMA16(a0, b0, acc);
            acc = MFMA16(a1, b1, acc);
            #pragma unroll
            for (int r = 0; r < 4; r++)          // C row = e_out, col = slot
                Ct[(nt * 16 + quad * 4 + r) * 72 + w * 16 + l16] = (bf16_t)acc[r];
        }
        __syncthreads();
        const int cnt = (Lc - c0 < 64) ? (Lc - c0) : 64;
        const size_t ob2 = ((size_t)(n * 16 + h)) * 131072 + c0;
        #pragma unroll
        for (int pass = 0; pass < 2; pass++) {
            int r = pass * 32 + (t >> 3);
            int cb8 = (t & 7) * 8;
            if (cb8 < cnt) {
                if (cb8 + 8 <= cnt) {
                    *(bf16x8*)&vcT[ob2 + (size_t)r * 2048 + cb8] =
                        *(const bf16x8*)&Ct[r * 72 + cb8];
                } else {
                    for (int q = cb8; q < cnt; q++)
                        vcT[ob2 + (size_t)r * 2048 + q] = Ct[r * 72 + q];
                }
            }
        }
        return;
    }

    // ---- y=0: K (compacted rows), 128 rows/block ----
    if (blockIdx.x >= 512) return;
    const int n = blockIdx.x >> 8;                // 256 blocks per batch
    const int c0 = (blockIdx.x & 255) * 8;        // 8 compacted tokens x 16 heads
    const int Lc = excl[n * 2049 + 2048];
    if (c0 >= Lc) return;

    float* Xs = (float*)smem;                         // [128][64] fp32, swizzled
    bf16_t* Ct2 = (bf16_t*)(smem + 32768);            // [128][72]

    #pragma unroll
    for (int j = 0; j < 8; j++) {
        int br = w * 32 + j * 4;
        int srow = br + (lane >> 4);
        int scol = ((lane & 15) ^ (srow & 15)) * 4;
        int csx = c0 + (srow >> 4); if (csx > Lc - 1) csx = Lc - 1;
        int hs = srow & 15;
        int ls = lmap[n * 2048 + csx];
        GLOAD_LDS16(&kin[((size_t)((n * 2048 + ls) * 16 + hs)) * 64 + scol], &Xs[br * 64]);
    }
    __syncthreads();

    const int rbase = w * 32;
    bf16x8 a[2][2];
    #pragma unroll
    for (int qs = 0; qs < 2; qs++) {
        int row = rbase + qs * 16 + l16;
        const char* rowp = (const char*)Xs + (size_t)row * 256;
        int swb = (row & 15) << 4;
        #pragma unroll
        for (int c = 0; c < 2; c++) {
            f32x4 lo = *(const f32x4*)(rowp + ((c * 128 + quad * 32) ^ swb));
            f32x4 hi = *(const f32x4*)(rowp + ((c * 128 + quad * 32 + 16) ^ swb));
            a[qs][c] = cvt8s(lo, hi);
        }
    }

    f32x4 acc[4][2];
    #pragma unroll
    for (int nt = 0; nt < 4; nt++) {
        bf16x8 b0 = *(const bf16x8*)&Wkb[(nt * 16 + l16) * 64 + quad * 8];
        bf16x8 b1 = *(const bf16x8*)&Wkb[(nt * 16 + l16) * 64 + 32 + quad * 8];
        #pragma unroll
        for (int qs = 0; qs < 2; qs++) {
            f32x4 z = {0.f, 0.f, 0.f, 0.f};
            z = MFMA16(a[qs][0], b0, z);
            z = MFMA16(a[qs][1], b1, z);
            acc[nt][qs] = z;
        }
    }

    #pragma unroll
    for (int nt = 0; nt < 4; nt++)
        #pragma unroll
        for (int qs = 0; qs < 2; qs++)
            #pragma unroll
            for (int r = 0; r < 4; r++)
                Ct2[(rbase + qs * 16 + quad * 4 + r) * 72 + nt * 16 + l16] = (bf16_t)acc[nt][qs][r];
    __syncthreads();

    #pragma unroll
    for (int it = 0; it < 4; it++) {
        int j = it * 32 + (t >> 3);
        bf16x8 val = *(const bf16x8*)&Ct2[j * 72 + (t & 7) * 8];
        int c = c0 + (j >> 4), h2 = j & 15;
        if (c < Lc)
            *(bf16x8*)&kc[(((size_t)(n * 16 + h2)) * 2048 + c) * 64 + (t & 7) * 8] = val;
    }
}

// ---------------------------------------------------------------------------
// Kernel 2: fused Q-projection + flash attention on COMPACTED K/V.
// 8 waves/block (512 threads), 16 Q-rows/wave, KVBLK=128 dbuf.
// Softmax denominator accumulated via ones-row MFMA (matrix pipe, no scalar
// lsum chain, no final shuffle reduce).
// ---------------------------------------------------------------------------
__global__ __launch_bounds__(512) void attn_kernel(
    const float* __restrict__ qin, const bf16_t* __restrict__ Wqb,
    const bf16_t* __restrict__ kc, const bf16_t* __restrict__ vcT,
    const int* __restrict__ excl, bf16_t* __restrict__ ao)
{
    __shared__ __align__(16) char smem[65536];
    bf16_t* KtP = (bf16_t*)smem;              // [2][128][64]
    bf16_t* VtP = (bf16_t*)(smem + 32768);    // [2][64][128]
#define KT(buf, r, c) KtP[(buf) * 8192 + (r) * 64 + (c)]
#define VT(buf, r, c) VtP[(buf) * 8192 + (r) * 128 + (c)]

    const int t = threadIdx.x;
    const int w = t >> 6, lane = t & 63, quad = lane >> 4, l16 = lane & 15;

    const int flat = blockIdx.x;
    const int xcd = flat & 7, slot = flat >> 3;
    const int nh = xcd * 4 + (slot >> 4), qb = slot & 15;
    const int n = nh >> 4, h = nh & 15;
    const size_t nhbase = (size_t)nh * 131072;

    const int Lc = excl[n * 2049 + 2048];
    const int ntiles = (Lc + 127) >> 7;
    const int rbase = w * 16;                 // this wave's 16 Q-rows

    // ---- Q projection prologue (overlays Kt as fp32 Xq, Vt[0] as bf16 Qt) --
    bf16x8 aq[2];
    {
        float* Xq = (float*)smem;                 // [128][64] fp32, swizzled
        bf16_t* Qt = (bf16_t*)(smem + 32768);     // [128][64] bf16, swizzled
        const int qrow0 = qb * 128;
        #pragma unroll
        for (int j = 0; j < 4; j++) {
            int br = w * 16 + j * 4;
            int srow = br + (lane >> 4);
            int scol = ((lane & 15) ^ (srow & 15)) * 4;
            GLOAD_LDS16(&qin[((size_t)(n * 2048 + qrow0 + srow)) * 1024 + h * 64 + scol],
                        &Xq[br * 64]);
        }
        __syncthreads();

        bf16x8 a[2];
        {
            int row = rbase + l16;
            const char* rowp = (const char*)Xq + (size_t)row * 256;
            int swb = (row & 15) << 4;
            #pragma unroll
            for (int c = 0; c < 2; c++) {
                f32x4 lo = *(const f32x4*)(rowp + ((c * 128 + quad * 32) ^ swb));
                f32x4 hi = *(const f32x4*)(rowp + ((c * 128 + quad * 32 + 16) ^ swb));
                a[c] = cvt8s(lo, hi);
            }
        }
        f32x4 pacc[4];
        #pragma unroll
        for (int nt = 0; nt < 4; nt++) {
            bf16x8 b0 = *(const bf16x8*)&Wqb[(nt * 16 + l16) * 64 + quad * 8];
            bf16x8 b1 = *(const bf16x8*)&Wqb[(nt * 16 + l16) * 64 + 32 + quad * 8];
            f32x4 z = {0.f, 0.f, 0.f, 0.f};
            z = MFMA16(a[0], b0, z);
            z = MFMA16(a[1], b1, z);
            pacc[nt] = z;
        }
        // store C-layout -> swizzled Qt (each wave stores/reads only its rows)
        #pragma unroll
        for (int nt = 0; nt < 4; nt++)
            #pragma unroll
            for (int r = 0; r < 4; r++) {
                int row = rbase + quad * 4 + r;
                int col = nt * 16 + l16;
                int byteoff = row * 128 + ((((col >> 3) ^ (row & 7)) << 4) | ((col & 7) << 1));
                *(bf16_t*)((char*)Qt + byteoff) = (bf16_t)pacc[nt][r];
            }
        {
            int row = rbase + l16;
            #pragma unroll
            for (int c = 0; c < 2; c++)
                aq[c] = *(const bf16x8*)((const char*)Qt + row * 128 +
                                         (((c * 4 + quad) ^ (row & 7)) << 4));
        }
        __syncthreads();   // all Qt reads done before Vt[0] is overwritten
    }

    // ones A-operand for denominator MFMA
    bf16x8 ones;
    #pragma unroll
    for (int j = 0; j < 8; j++) ones[j] = (bf16_t)1.0f;

    f32x4 o[4];
    f32x4 acc_l = {0.f, 0.f, 0.f, 0.f};      // all rows = per-q denominator
    #pragma unroll
    for (int dt = 0; dt < 4; dt++) {
        o[dt][0] = 0.f; o[dt][1] = 0.f; o[dt][2] = 0.f; o[dt][3] = 0.f;
    }

    // staging source swizzles
    const int ksrow = lane >> 3;                          // K: row within 8
    const int kscol = ((lane & 7) ^ (lane >> 3)) * 8;     // K: elements
    // read swizzles
    const int swr = l16 & 7;
    const int ck0 = (quad ^ swr) * 8;                     // Kt low 64B half
    const int ck1 = ((quad + 4) ^ swr) * 8;               // Kt high 64B half

#define STAGE_KV(buf, kn)                                                     \
    {                                                                         \
        _Pragma("unroll")                                                     \
        for (int j = 0; j < 2; j++) {                                         \
            int rb = w * 16 + j * 8;                                          \
            GLOAD_LDS16(&kc[nhbase + (size_t)((kn) + rb + ksrow) * 64 + kscol],\
                        &KT(buf, rb, 0));                                     \
        }                                                                     \
        _Pragma("unroll")                                                     \
        for (int j = 0; j < 2; j++) {                                         \
            int rb = w * 8 + j * 4;                                           \
            int d = rb + (lane >> 4);                                         \
            int sc = ((lane & 15) ^ (d & 15)) * 8;                            \
            GLOAD_LDS16(&vcT[nhbase + (size_t)d * 2048 + (kn) + sc],          \
                        &VT(buf, rb, 0));                                     \
        }                                                                     \
    }

    STAGE_KV(0, 0);

    for (int i = 0; i < ntiles; i++) {
        const int cb = i & 1, nb = cb ^ 1;
        const int k0 = i * 128;
        __syncthreads();

        if (i + 1 < ntiles) STAGE_KV(nb, k0 + 128);

        #pragma unroll
        for (int hf = 0; hf < 2; hf++) {
            const int kh = k0 + hf * 64;

            // QK^T: lane (quad,l16) gets P[k = kh + ct*16+quad*4+r][q = l16]
            f32x4 st[4];
            __builtin_amdgcn_s_setprio(1);
            #pragma unroll
            for (int ct = 0; ct < 4; ct++) {
                bf16x8 kb0 = *(const bf16x8*)&KT(cb, hf * 64 + ct * 16 + l16, ck0);
                bf16x8 kb1 = *(const bf16x8*)&KT(cb, hf * 64 + ct * 16 + l16, ck1);
                f32x4 acc = {0.f, 0.f, 0.f, 0.f};
                acc = MFMA16(kb0, aq[0], acc);
                acc = MFMA16(kb1, aq[1], acc);
                st[ct] = acc;
            }
            __builtin_amdgcn_s_setprio(0);

            // softmax numerator: p = 2^score (log2e folded into Wqb)
            if (kh + 64 <= Lc) {
                #pragma unroll
                for (int ct = 0; ct < 4; ct++)
                    #pragma unroll
                    for (int r = 0; r < 4; r++)
                        st[ct][r] = exp2_fast(st[ct][r]);
            } else {
                #pragma unroll
                for (int ct = 0; ct < 4; ct++)
                    #pragma unroll
                    for (int r = 0; r < 4; r++) {
                        int kk = kh + ct * 16 + quad * 4 + r;
                        st[ct][r] = (kk < Lc) ? exp2_fast(st[ct][r]) : 0.0f;
                    }
            }

            // in-register P -> B-operand redistribution (cvt_pk + permlane)
            bf16x8 bp[2];
            {
                unsigned u[4][2];
                #pragma unroll
                for (int ct = 0; ct < 4; ct++) {
                    u[ct][0] = cvt_pk_bf16(st[ct][0], st[ct][1]);
                    u[ct][1] = cvt_pk_bf16(st[ct][2], st[ct][3]);
                }
                #pragma unroll
                for (int hh = 0; hh < 2; hh++) {
                    unsigned b0 = u[2 * hh][0], b2 = u[2 * hh + 1][0];
                    xchg_quads(b0, b2);
                    unsigned b1 = u[2 * hh][1], b3 = u[2 * hh + 1][1];
                    xchg_quads(b1, b3);
                    u32x4 q4 = {b0, b1, b2, b3};
                    bp[hh] = __builtin_bit_cast(bf16x8, q4);
                }
            }

            __builtin_amdgcn_s_setprio(1);
            // denominator: D[row][q] = sum_k P[k][q]  (A = ones)
            acc_l = MFMA16(ones, bp[0], acc_l);
            acc_l = MFMA16(ones, bp[1], acc_l);
            #pragma unroll
            for (int dt = 0; dt < 4; dt++) {
                bf16x8 va0 = *(const bf16x8*)&VT(cb, dt * 16 + l16, ((hf * 8 + quad) ^ l16) * 8);
                bf16x8 va1 = *(const bf16x8*)&VT(cb, dt * 16 + l16, ((hf * 8 + 4 + quad) ^ l16) * 8);
                o[dt] = MFMA16(va0, bp[0], o[dt]);
                o[dt] = MFMA16(va1, bp[1], o[dt]);
            }
            __builtin_amdgcn_s_setprio(0);
        }
    }

    {
        float inv = 1.0f / acc_l[0];          // all acc_l rows equal: per-q sum
        const int q = qb * 128 + w * 16 + l16;
        const size_t base = ((size_t)n * 2048 + q) * 1024 + h * 64;
        #pragma unroll
        for (int dt = 0; dt < 4; dt++) {
            bf16x4 ov;
            #pragma unroll
            for (int r = 0; r < 4; r++) ov[r] = (bf16_t)(o[dt][r] * inv);
            *(bf16x4*)&ao[base + dt * 16 + quad * 4] = ov;
        }
    }
#undef KT
#undef VT
#undef STAGE_KV
}

// ---------------------------------------------------------------------------
// Kernel 3: out = X @ Wob^T + bo. 128x64 tiles, 512 blocks (3 blocks/CU).
// ---------------------------------------------------------------------------
__global__ __launch_bounds__(256, 2) void out_proj_kernel(
    const bf16_t* __restrict__ X, const bf16_t* __restrict__ Wob,
    const float* __restrict__ bo, float* __restrict__ out)
{
    __shared__ bf16_t Xs[2][128][64];
    __shared__ bf16_t Ws[2][64][64];

    const int t = threadIdx.x;
    const int w = t >> 6, lane = t & 63, quad = lane >> 4, l16 = lane & 15;
    const int Mbase = blockIdx.x * 128;
    const int Nbase = blockIdx.y * 64;
    const int mrow = (w & 1) * 64;
    const int ncol = (w >> 1) * 32;

    const int scol = ((lane & 7) ^ (lane >> 3)) * 8;
    const int swr  = l16 & 7;

    f32x4 acc[4][2];
    #pragma unroll
    for (int mi = 0; mi < 4; mi++)
        #pragma unroll
        for (int ni = 0; ni < 2; ni++) {
            acc[mi][ni][0] = 0.f; acc[mi][ni][1] = 0.f;
            acc[mi][ni][2] = 0.f; acc[mi][ni][3] = 0.f;
        }

    #pragma unroll
    for (int j = 0; j < 4; j++) {
        int br = w * 32 + j * 8;
        GLOAD_LDS16(&X[(size_t)(Mbase + br + (lane >> 3)) * 1024 + scol], &Xs[0][br][0]);
    }
    #pragma unroll
    for (int j = 0; j < 2; j++) {
        int br = w * 16 + j * 8;
        GLOAD_LDS16(&Wob[(size_t)(Nbase + br + (lane >> 3)) * 1024 + scol], &Ws[0][br][0]);
    }

    for (int i = 0; i < 16; i++) {
        const int cb = i & 1, nb = cb ^ 1;
        __syncthreads();

        if (i < 15) {
            const int kn = (i + 1) * 64;
            #pragma unroll
            for (int j = 0; j < 4; j++) {
                int br = w * 32 + j * 8;
                GLOAD_LDS16(&X[(size_t)(Mbase + br + (lane >> 3)) * 1024 + kn + scol],
                            &Xs[nb][br][0]);
            }
            #pragma unroll
            for (int j = 0; j < 2; j++) {
                int br = w * 16 + j * 8;
                GLOAD_LDS16(&Wob[(size_t)(Nbase + br + (lane >> 3)) * 1024 + kn + scol],
                            &Ws[nb][br][0]);
            }
        }

        #pragma unroll
        for (int c = 0; c < 2; c++) {
            bf16x8 bfr[2];
            #pragma unroll
            for (int ni = 0; ni < 2; ni++)
                bfr[ni] = *(const bf16x8*)&Ws[cb][ncol + ni * 16 + l16][((c * 4 + quad) ^ swr) * 8];
            #pragma unroll
            for (int mi = 0; mi < 4; mi++) {
                bf16x8 afr = *(const bf16x8*)&Xs[cb][mrow + mi * 16 + l16][((c * 4 + quad) ^ swr) * 8];
                #pragma unroll
                for (int ni = 0; ni < 2; ni++)
                    acc[mi][ni] = MFMA16(afr, bfr[ni], acc[mi][ni]);
            }
        }
    }

    #pragma unroll
    for (int ni = 0; ni < 2; ni++) {
        float b = bo[Nbase + ncol + ni * 16 + l16];
        #pragma unroll
        for (int mi = 0; mi < 4; mi++) {
            #pragma unroll
            for (int r = 0; r < 4; r++) {
                int row = Mbase + mrow + mi * 16 + quad * 4 + r;
                out[(size_t)row * 1024 + Nbase + ncol + ni * 16 + l16] = acc[mi][ni][r] + b;
            }
        }
    }
}

// ---------------------------------------------------------------------------
extern "C" void kernel_launch(void* const* d_in, const int* in_sizes, int n_in,
                              void* d_out, int out_size, void* d_ws, size_t ws_size,
                              hipStream_t stream)
{
    const float* qin = (const float*)d_in[0];
    const float* kin = (const float*)d_in[1];
    const float* vin = (const float*)d_in[2];
    const int*   msk = (const int*)d_in[3];
    const float* Wq  = (const float*)d_in[4];
    const float* Wk  = (const float*)d_in[5];
    const float* Wv  = (const float*)d_in[6];
    const float* Wo  = (const float*)d_in[7];
    const float* bo  = (const float*)d_in[8];
    float* out = (float*)d_out;

    bf16_t* ws  = (bf16_t*)d_ws;
    bf16_t* kc  = ws + 4194304;        // (n,h,c,d)  4M (first Lc rows valid)
    bf16_t* vcT = ws + 8388608;        // (n,h,d,c)  4M (first Lc cols valid)
    bf16_t* ao  = ws + 12582912;       // (n,l,h*64+d) 4M
    bf16_t* Wob = ws + 16777216;       // bf16 Wo   1M
    int* excl   = (int*)(ws + 17825792);  // 2 x 2049 ints
    int* lmap   = excl + 4100;            // 2 x 2048 ints (compacted -> token)
    bf16_t* Wqb = (bf16_t*)(lmap + 4096); // 64x64 bf16 (scaled)
    bf16_t* Wkb = Wqb + 4096;
    bf16_t* Wvb = Wkb + 4096;

    scan_kernel<<<5, 256, 0, stream>>>(msk, excl, lmap, Wq, Wk, Wv, Wqb, Wkb, Wvb);
    qkv_proj_kernel<<<dim3(1024, 3), 256, 0, stream>>>(kin, vin, Wkb, Wvb, Wo,
                                                        excl, lmap, kc, vcT, Wob);
    attn_kernel<<<dim3(512), 512, 0, stream>>>(qin, Wqb, kc, vcT, excl, ao);
    out_proj_kernel<<<dim3(32, 16), 256, 0, stream>>>(ao, Wob, bo, out);
}